// Round 1
// baseline (28.143 us; speedup 1.0000x reference)
//
#include <hip/hip_runtime.h>
#include <math.h>

#define D_MODEL 16
#define HIDDEN  64
#define B_SZ    32
#define IN_SZ   512
#define OUT_SZ  256

// div_j = 10000^(-j/8), j = 0..7  (f32-accurate constants)
__device__ __constant__ float c_div[8] = {
    1.0f, 0.31622776601683794f, 0.1f, 0.031622776601683794f,
    0.01f, 0.0031622776601683794f, 0.001f, 0.00031622776601683794f
};

__global__ __launch_bounds__(512) void vnn_kernel(
    const float* __restrict__ x,
    const float* __restrict__ w1,  const float* __restrict__ b1,
    const float* __restrict__ w2,  const float* __restrict__ b2,
    const float* __restrict__ bw1, const float* __restrict__ bb1,
    const float* __restrict__ bw2, const float* __restrict__ bb2,
    float* __restrict__ out)
{
    __shared__ float w1s[33 * 64];
    __shared__ float bw1s[17 * 64];
    __shared__ float b1s[64], w2s[64], bb1s[64], bw2s[64];
    __shared__ float xs[IN_SZ];
    __shared__ float Wv[IN_SZ];
    __shared__ float ppar[64];
    __shared__ float b2s, bb2s;

    const int t = threadIdx.x;
    const int b = blockIdx.x;

    // ---- stage everything to LDS ----
    for (int i = t; i < 33 * 64; i += 512) w1s[i] = w1[i];
    for (int i = t; i < 17 * 64; i += 512) bw1s[i] = bw1[i];
    if (t < 64) { b1s[t] = b1[t]; w2s[t] = w2[t]; bb1s[t] = bb1[t]; bw2s[t] = bw2[t]; }
    if (t == 0) { b2s = b2[0]; bb2s = bb2[0]; }
    xs[t] = x[b * IN_SZ + t];
    __syncthreads();

    // ---- per-64 partial sums of x (parity preserved: (t + 64j) % 2 == t % 2) ----
    if (t < 64) {
        float p = 0.f;
        #pragma unroll
        for (int j = 0; j < 8; ++j) p += xs[t + 64 * j];
        ppar[t] = p;
    }

    // ---- W[b, m] for m = t in [0, 512):
    //      relu(pos_enc(m) @ w1[0:16] + pos_enc(m % 256) @ w1[16:32]
    //           + x[b,m]*w1[32] + b1) @ w2 + b2
    {
        const int m  = t;
        const int mo = m & 255;
        float pe1[16], pe2[16];
        #pragma unroll
        for (int j = 0; j < 8; ++j) {
            float a1 = (float)m  * c_div[j];
            float a2 = (float)mo * c_div[j];
            pe1[2 * j]     = sinf(a1);
            pe1[2 * j + 1] = cosf(a1);
            pe2[2 * j]     = sinf(a2);
            pe2[2 * j + 1] = cosf(a2);
        }
        const float xv = xs[m];
        float acc = 0.f;
        #pragma unroll 4
        for (int h = 0; h < HIDDEN; ++h) {
            float hv = b1s[h] + xv * w1s[32 * 64 + h];
            #pragma unroll
            for (int j = 0; j < 16; ++j) {
                hv += pe1[j] * w1s[j * 64 + h];
                hv += pe2[j] * w1s[(16 + j) * 64 + h];
            }
            acc += fmaxf(hv, 0.f) * w2s[h];
        }
        Wv[m] = acc + b2s;
    }
    __syncthreads();

    // ---- out[b,o] = se*W[o] + so*W[o+256]; then fused bias MLP; write ----
    if (t < OUT_SZ) {
        float se = 0.f, so = 0.f;
        #pragma unroll
        for (int j = 0; j < 32; ++j) { se += ppar[2 * j]; so += ppar[2 * j + 1]; }

        const float outv = Wv[t] * se + Wv[t + 256] * so;

        float peo[16];
        #pragma unroll
        for (int j = 0; j < 8; ++j) {
            float a = (float)t * c_div[j];
            peo[2 * j]     = sinf(a);
            peo[2 * j + 1] = cosf(a);
        }
        float bacc = 0.f;
        #pragma unroll 4
        for (int h = 0; h < HIDDEN; ++h) {
            float hv = bb1s[h] + outv * bw1s[16 * 64 + h];
            #pragma unroll
            for (int j = 0; j < 16; ++j) hv += peo[j] * bw1s[j * 64 + h];
            bacc += fmaxf(hv, 0.f) * bw2s[h];
        }
        out[b * OUT_SZ + t] = outv + bacc + bb2s;
    }
}

extern "C" void kernel_launch(void* const* d_in, const int* in_sizes, int n_in,
                              void* d_out, int out_size, void* d_ws, size_t ws_size,
                              hipStream_t stream) {
    const float* x   = (const float*)d_in[0];
    const float* w1  = (const float*)d_in[1];
    const float* b1  = (const float*)d_in[2];
    const float* w2  = (const float*)d_in[3];
    const float* b2  = (const float*)d_in[4];
    const float* bw1 = (const float*)d_in[5];
    const float* bb1 = (const float*)d_in[6];
    const float* bw2 = (const float*)d_in[7];
    const float* bb2 = (const float*)d_in[8];
    float* out = (float*)d_out;

    vnn_kernel<<<B_SZ, 512, 0, stream>>>(x, w1, b1, w2, b2, bw1, bb1, bw2, bb2, out);
}

// Round 2
// 24.601 us; speedup vs baseline: 1.1440x; 1.1440x over previous
//
#include <hip/hip_runtime.h>
#include <math.h>

// out[b,o] = W(b,o)*sum_even(x[b]) + W(b,o+256)*sum_odd(x[b]) + bias_mlp(o, out)
// where W(b,m) = relu(pe(m)@w1[0:16] + pe(m&255)@w1[16:32] + x[b,m]*w1[32] + b1) @ w2 + b2
// Grid: 64 blocks = 32 batches x 2 output-halves; block = 256 threads = 128 o x 2 (m=o / m=o+256).
// Weights are wave-uniform -> scalar s_load + v_fmac with SGPR operand; no LDS in hot loops.

__global__ __launch_bounds__(256) void vnn_kernel(
    const float* __restrict__ x,
    const float* __restrict__ w1,  const float* __restrict__ b1,
    const float* __restrict__ w2,  const float* __restrict__ b2,
    const float* __restrict__ bw1, const float* __restrict__ bb1,
    const float* __restrict__ bw2, const float* __restrict__ bb2,
    float* __restrict__ out)
{
    __shared__ float Wv[256];
    __shared__ float pp[4][2];

    const int t  = threadIdx.x;
    const int b  = blockIdx.x >> 1;
    const int oh = blockIdx.x & 1;
    const int ol = t & 127;
    const int hi = t >> 7;
    const int o  = oh * 128 + ol;
    const int m  = o + 256 * hi;

    // ---- parity partial sums of x[b,:] (both blocks of a batch compute the same) ----
    {
        float v = x[b * 512 + t] + x[b * 512 + t + 256];  // t and t+256 share parity
        #pragma unroll
        for (int msk = 2; msk <= 32; msk <<= 1) v += __shfl_xor(v, msk, 64);
        const int wid = t >> 6, lane = t & 63;
        if (lane < 2) pp[wid][lane] = v;  // lane0: even-t sum, lane1: odd-t sum
    }

    // ---- positional encodings via v_sin/v_cos (input in revolutions) ----
    // rcs[j] = 10000^(-j/8) / (2*pi)
    float p1s[8], p1c[8], p2s[8], p2c[8];
    {
        const float rcs[8] = {
            0.15915494309189535f,  0.05032921210448703f,
            0.015915494309189535f, 0.005032921210448703f,
            0.0015915494309189535f,0.0005032921210448703f,
            0.00015915494309189535f, 5.0329212104487035e-05f };
        const float fm = (float)m, fo = (float)o;
        #pragma unroll
        for (int j = 0; j < 8; ++j) {
            float r1 = fm * rcs[j]; r1 -= floorf(r1);
            float r2 = fo * rcs[j]; r2 -= floorf(r2);
            p1s[j] = __builtin_amdgcn_sinf(r1);
            p1c[j] = __builtin_amdgcn_cosf(r1);
            p2s[j] = __builtin_amdgcn_sinf(r2);
            p2c[j] = __builtin_amdgcn_cosf(r2);
        }
    }

    // ---- weight MLP for index m: 64 register accumulators, j-outer so each
    //      w1 row (64 contiguous floats) is a uniform scalar load ----
    const float xv = x[b * 512 + m];
    float hv[64];
    #pragma unroll
    for (int h = 0; h < 64; ++h) hv[h] = b1[h] + xv * w1[32 * 64 + h];
    #pragma unroll
    for (int r = 0; r < 16; ++r) {
        const float cf = (r & 1) ? p1c[r >> 1] : p1s[r >> 1];  // pe(m)
        #pragma unroll
        for (int h = 0; h < 64; ++h) hv[h] += cf * w1[r * 64 + h];
    }
    #pragma unroll
    for (int r = 0; r < 16; ++r) {
        const float cf = (r & 1) ? p2c[r >> 1] : p2s[r >> 1];  // pe(m & 255) == pe(o)
        #pragma unroll
        for (int h = 0; h < 64; ++h) hv[h] += cf * w1[(16 + r) * 64 + h];
    }
    float acc = b2[0];
    #pragma unroll
    for (int h = 0; h < 64; ++h) acc += fmaxf(hv[h], 0.f) * w2[h];
    Wv[t] = acc;   // t == hi*128 + ol
    __syncthreads();

    // ---- combine + bias MLP (all 256 threads compute; redundant x2 keeps CF uniform) ----
    float se = 0.f, so = 0.f;
    #pragma unroll
    for (int w = 0; w < 4; ++w) { se += pp[w][0]; so += pp[w][1]; }
    const float outv = Wv[ol] * se + Wv[128 + ol] * so;

    float bh[64];
    #pragma unroll
    for (int h = 0; h < 64; ++h) bh[h] = bb1[h] + outv * bw1[16 * 64 + h];
    #pragma unroll
    for (int r = 0; r < 16; ++r) {
        const float cf = (r & 1) ? p2c[r >> 1] : p2s[r >> 1];  // pe(o)
        #pragma unroll
        for (int h = 0; h < 64; ++h) bh[h] += cf * bw1[r * 64 + h];
    }
    float bacc = bb2[0];
    #pragma unroll
    for (int h = 0; h < 64; ++h) bacc += fmaxf(bh[h], 0.f) * bw2[h];

    if (t < 128) out[b * 256 + o] = outv + bacc;
}

extern "C" void kernel_launch(void* const* d_in, const int* in_sizes, int n_in,
                              void* d_out, int out_size, void* d_ws, size_t ws_size,
                              hipStream_t stream) {
    const float* x   = (const float*)d_in[0];
    const float* w1  = (const float*)d_in[1];
    const float* b1  = (const float*)d_in[2];
    const float* w2  = (const float*)d_in[3];
    const float* b2  = (const float*)d_in[4];
    const float* bw1 = (const float*)d_in[5];
    const float* bb1 = (const float*)d_in[6];
    const float* bw2 = (const float*)d_in[7];
    const float* bb2 = (const float*)d_in[8];
    float* out = (float*)d_out;

    vnn_kernel<<<64, 256, 0, stream>>>(x, w1, b1, w2, b2, bw1, bb1, bw2, bb2, out);
}

// Round 3
// 14.664 us; speedup vs baseline: 1.9192x; 1.6776x over previous
//
#include <hip/hip_runtime.h>
#include <math.h>

// out[b,o] = W(b,o)*sum_even(x[b]) + W(b,o+256)*sum_odd(x[b]) + bias_mlp(o, out)
// W(b,m)   = relu(PE1[m] + x[b,m]*w1[32]) @ w2 + b2,  PE1[m] = pe(m)@w1[0:16] + pe(m&255)@w1[16:32] + b1
// bias     = relu(PEO[o] + out[b,o]*bw1[16]) @ bw2 + bb2, PEO[o] = pe(o)@bw1[0:16] + bb1
// PE1/PEO are batch-independent -> precomputed once in pe_kernel (kernel A) into d_ws.

// rcs[j] = 10000^(-j/8) / (2*pi)   (v_sin/v_cos take revolutions)
__device__ __constant__ float c_rcs[8] = {
    0.15915494309189535f,   0.05032921210448703f,
    0.015915494309189535f,  0.005032921210448703f,
    0.0015915494309189535f, 0.0005032921210448703f,
    0.00015915494309189535f, 5.0329212104487035e-05f };

// ---------------- Kernel A: PE tables ----------------
// blocks 0..7: PE1 rows m = blk*64 + (t>>2), h-chunk q = t&3 (16 h each)
// blocks 8..11: PEO rows o = (blk-8)*64 + (t>>2)
__global__ __launch_bounds__(256) void pe_kernel(
    const float* __restrict__ w1,  const float* __restrict__ b1,
    const float* __restrict__ bw1, const float* __restrict__ bb1,
    float* __restrict__ ws)
{
    __shared__ __attribute__((aligned(16))) float wls[2048];
    const int t   = threadIdx.x;
    const int blk = blockIdx.x;
    const bool is1 = blk < 8;
    float* PE1 = ws;              // 512*64
    float* PEO = ws + 512 * 64;   // 256*64

    if (is1) {  // w1 rows 0..31 (2048 floats)
        float4* dst = (float4*)wls;
        const float4* src = (const float4*)w1;
        dst[t] = src[t];
        dst[t + 256] = src[t + 256];
    } else {    // bw1 rows 0..15 (1024 floats)
        float4* dst = (float4*)wls;
        const float4* src = (const float4*)bw1;
        if (t < 256) dst[t] = src[t];
    }
    __syncthreads();

    const int ml = t >> 2;
    const int q  = t & 3;

    if (is1) {
        const int m  = blk * 64 + ml;
        const int mo = m & 255;
        float s1[8], c1[8], s2[8], c2[8];
        #pragma unroll
        for (int j = 0; j < 8; ++j) {
            float r1 = (float)m  * c_rcs[j]; r1 -= floorf(r1);
            float r2 = (float)mo * c_rcs[j]; r2 -= floorf(r2);
            s1[j] = __builtin_amdgcn_sinf(r1); c1[j] = __builtin_amdgcn_cosf(r1);
            s2[j] = __builtin_amdgcn_sinf(r2); c2[j] = __builtin_amdgcn_cosf(r2);
        }
        float4 a[4];
        #pragma unroll
        for (int k = 0; k < 4; ++k) a[k] = *(const float4*)&b1[q * 16 + k * 4];
        #pragma unroll
        for (int j = 0; j < 8; ++j) {
            #pragma unroll
            for (int k = 0; k < 4; ++k) {
                const float4 v0 = *(const float4*)&wls[(2*j)      * 64 + q*16 + k*4];
                const float4 v1 = *(const float4*)&wls[(2*j + 1)  * 64 + q*16 + k*4];
                const float4 v2 = *(const float4*)&wls[(16 + 2*j) * 64 + q*16 + k*4];
                const float4 v3 = *(const float4*)&wls[(17 + 2*j) * 64 + q*16 + k*4];
                a[k].x = fmaf(s1[j], v0.x, fmaf(c1[j], v1.x, fmaf(s2[j], v2.x, fmaf(c2[j], v3.x, a[k].x))));
                a[k].y = fmaf(s1[j], v0.y, fmaf(c1[j], v1.y, fmaf(s2[j], v2.y, fmaf(c2[j], v3.y, a[k].y))));
                a[k].z = fmaf(s1[j], v0.z, fmaf(c1[j], v1.z, fmaf(s2[j], v2.z, fmaf(c2[j], v3.z, a[k].z))));
                a[k].w = fmaf(s1[j], v0.w, fmaf(c1[j], v1.w, fmaf(s2[j], v2.w, fmaf(c2[j], v3.w, a[k].w))));
            }
        }
        #pragma unroll
        for (int k = 0; k < 4; ++k)
            *(float4*)&PE1[m * 64 + q * 16 + k * 4] = a[k];
    } else {
        const int o = (blk - 8) * 64 + ml;
        float s1[8], c1[8];
        #pragma unroll
        for (int j = 0; j < 8; ++j) {
            float r1 = (float)o * c_rcs[j]; r1 -= floorf(r1);
            s1[j] = __builtin_amdgcn_sinf(r1); c1[j] = __builtin_amdgcn_cosf(r1);
        }
        float4 a[4];
        #pragma unroll
        for (int k = 0; k < 4; ++k) a[k] = *(const float4*)&bb1[q * 16 + k * 4];
        #pragma unroll
        for (int j = 0; j < 8; ++j) {
            #pragma unroll
            for (int k = 0; k < 4; ++k) {
                const float4 v0 = *(const float4*)&wls[(2*j)     * 64 + q*16 + k*4];
                const float4 v1 = *(const float4*)&wls[(2*j + 1) * 64 + q*16 + k*4];
                a[k].x = fmaf(s1[j], v0.x, fmaf(c1[j], v1.x, a[k].x));
                a[k].y = fmaf(s1[j], v0.y, fmaf(c1[j], v1.y, a[k].y));
                a[k].z = fmaf(s1[j], v0.z, fmaf(c1[j], v1.z, a[k].z));
                a[k].w = fmaf(s1[j], v0.w, fmaf(c1[j], v1.w, a[k].w));
            }
        }
        #pragma unroll
        for (int k = 0; k < 4; ++k)
            *(float4*)&PEO[o * 64 + q * 16 + k * 4] = a[k];
    }
}

// ---------------- Kernel B: per-batch main ----------------
// 64 blocks = (batch b, half oh) x 256 threads; thread = (hi = t>>7, ol = t&127),
// handles m = oh*128+ol + 256*hi for the weight MLP and o = oh*128+ol for bias.
__global__ __launch_bounds__(256) void vnn_main(
    const float* __restrict__ x,
    const float* __restrict__ w1, const float* __restrict__ w2,
    const float* __restrict__ b2,
    const float* __restrict__ bw1, const float* __restrict__ bw2,
    const float* __restrict__ bb2,
    const float* __restrict__ ws,
    float* __restrict__ out)
{
    __shared__ __attribute__((aligned(16))) float w1c[64], w2s[64], bwc[64], bw2s[64];
    __shared__ float Wv[256];
    __shared__ float pp[4][2];

    const int t  = threadIdx.x;
    const int b  = blockIdx.x >> 1;
    const int oh = blockIdx.x & 1;
    const int ol = t & 127;
    const int hi = t >> 7;
    const int o  = oh * 128 + ol;
    const int m  = o + 256 * hi;
    const float* PE1 = ws;
    const float* PEO = ws + 512 * 64;

    if (t < 64) {
        w1c[t]  = w1[32 * 64 + t];
        w2s[t]  = w2[t];
        bwc[t]  = bw1[16 * 64 + t];
        bw2s[t] = bw2[t];
    }
    {   // parity partial sums of x[b,:]
        float v = x[b * 512 + t] + x[b * 512 + t + 256];
        #pragma unroll
        for (int msk = 2; msk <= 32; msk <<= 1) v += __shfl_xor(v, msk, 64);
        if ((t & 63) < 2) pp[t >> 6][t & 63] = v;
    }
    const float xv = x[b * 512 + m];
    __syncthreads();

    float acc = b2[0];
    #pragma unroll
    for (int c = 0; c < 4; ++c) {
        float4 p[4], wa[4], wb[4];
        #pragma unroll
        for (int k = 0; k < 4; ++k) {
            p[k]  = *(const float4*)&PE1[m * 64 + c * 16 + k * 4];
            wa[k] = *(const float4*)&w1c[c * 16 + k * 4];
            wb[k] = *(const float4*)&w2s[c * 16 + k * 4];
        }
        #pragma unroll
        for (int k = 0; k < 4; ++k) {
            acc += fmaxf(fmaf(xv, wa[k].x, p[k].x), 0.f) * wb[k].x;
            acc += fmaxf(fmaf(xv, wa[k].y, p[k].y), 0.f) * wb[k].y;
            acc += fmaxf(fmaf(xv, wa[k].z, p[k].z), 0.f) * wb[k].z;
            acc += fmaxf(fmaf(xv, wa[k].w, p[k].w), 0.f) * wb[k].w;
        }
    }
    Wv[t] = acc;
    __syncthreads();

    float se = 0.f, so = 0.f;
    #pragma unroll
    for (int w = 0; w < 4; ++w) { se += pp[w][0]; so += pp[w][1]; }
    const float outv = Wv[ol] * se + Wv[128 + ol] * so;

    float acc2 = bb2[0];
    #pragma unroll
    for (int c = 0; c < 4; ++c) {
        float4 p[4], wa[4], wb[4];
        #pragma unroll
        for (int k = 0; k < 4; ++k) {
            p[k]  = *(const float4*)&PEO[o * 64 + c * 16 + k * 4];
            wa[k] = *(const float4*)&bwc[c * 16 + k * 4];
            wb[k] = *(const float4*)&bw2s[c * 16 + k * 4];
        }
        #pragma unroll
        for (int k = 0; k < 4; ++k) {
            acc2 += fmaxf(fmaf(outv, wa[k].x, p[k].x), 0.f) * wb[k].x;
            acc2 += fmaxf(fmaf(outv, wa[k].y, p[k].y), 0.f) * wb[k].y;
            acc2 += fmaxf(fmaf(outv, wa[k].z, p[k].z), 0.f) * wb[k].z;
            acc2 += fmaxf(fmaf(outv, wa[k].w, p[k].w), 0.f) * wb[k].w;
        }
    }
    if (t < 128) out[b * 256 + o] = outv + acc2;
}

extern "C" void kernel_launch(void* const* d_in, const int* in_sizes, int n_in,
                              void* d_out, int out_size, void* d_ws, size_t ws_size,
                              hipStream_t stream) {
    const float* x   = (const float*)d_in[0];
    const float* w1  = (const float*)d_in[1];
    const float* b1  = (const float*)d_in[2];
    const float* w2  = (const float*)d_in[3];
    const float* b2  = (const float*)d_in[4];
    const float* bw1 = (const float*)d_in[5];
    const float* bb1 = (const float*)d_in[6];
    const float* bw2 = (const float*)d_in[7];
    const float* bb2 = (const float*)d_in[8];
    float* ws  = (float*)d_ws;
    float* out = (float*)d_out;

    pe_kernel<<<12, 256, 0, stream>>>(w1, b1, bw1, bb1, ws);
    vnn_main<<<64, 256, 0, stream>>>(x, w1, w2, b2, bw1, bw2, bb2, ws, out);
}

// Round 4
// 11.316 us; speedup vs baseline: 2.4870x; 1.2958x over previous
//
#include <hip/hip_runtime.h>
#include <math.h>

// Fully fused, single dispatch.
// out[b,o] = W(b,o)*se + W(b,o+256)*so + bias_mlp(o, out), where
//   W(b,m) = relu(pe(m)@w1[0:16] + pe(m&255)@w1[16:32] + x[b,m]*w1[32] + b1) @ w2 + b2
//   se/so  = sums of even/odd-indexed x[b,:]
//   bias   = relu(pe(o)@bw1[0:16] + out*bw1[16] + bb1) @ bw2 + bb2
// Grid: 256 blocks = 32 batches x 8 o-groups (32 outputs each) -> 1 block/CU.
// Threads: t = q*64 + l; wave q owns h-slice [q*16, q*16+16); lane l -> (oi=l&31, hi=l>>5),
//   m = og*32 + oi + 256*hi.  All weight LDS reads are wave-uniform broadcasts.
// Note pe(m & 255) == pe(o) for BOTH halves (m<512), so bias MLP reuses the same trig.

// rcs[j] = 10000^(-j/8) / (2*pi)   (v_sin/v_cos take revolutions)
__device__ __constant__ float c_rcs[8] = {
    0.15915494309189535f,   0.05032921210448703f,
    0.015915494309189535f,  0.005032921210448703f,
    0.0015915494309189535f, 0.0005032921210448703f,
    0.00015915494309189535f, 5.0329212104487035e-05f };

__global__ __launch_bounds__(256) void vnn_fused(
    const float* __restrict__ x,
    const float* __restrict__ w1,  const float* __restrict__ b1,
    const float* __restrict__ w2,  const float* __restrict__ b2,
    const float* __restrict__ bw1, const float* __restrict__ bb1,
    const float* __restrict__ bw2, const float* __restrict__ bb2,
    float* __restrict__ out)
{
    __shared__ __attribute__((aligned(16))) float w1s[33 * 64];
    __shared__ __attribute__((aligned(16))) float bw1s[17 * 64];
    __shared__ __attribute__((aligned(16))) float b1s[64], w2s[64], bb1s[64], bw2s[64];
    __shared__ float part[4][64];
    __shared__ float part2[4][32];
    __shared__ float pp[4][2];
    __shared__ float b2s_, bb2s_;

    const int t  = threadIdx.x;
    const int b  = blockIdx.x >> 3;
    const int og = blockIdx.x & 7;
    const int l  = t & 63;
    const int q  = __builtin_amdgcn_readfirstlane(t >> 6);  // wave id = h-slice

    // ---- stage weights to LDS (coalesced float4) ----
    {
        const float4* s1 = (const float4*)w1;  float4* d1 = (float4*)w1s;
        #pragma unroll
        for (int i = 0; i < 2; ++i) d1[t + 256 * i] = s1[t + 256 * i];   // 512
        if (t < 16) d1[512 + t] = s1[512 + t];                           // 528 total
        const float4* s2 = (const float4*)bw1; float4* d2 = (float4*)bw1s;
        d2[t] = s2[t];                                                   // 256
        if (t < 16) d2[256 + t] = s2[256 + t];                           // 272 total
        if (t < 64) { b1s[t] = b1[t]; w2s[t] = w2[t]; bb1s[t] = bb1[t]; bw2s[t] = bw2[t]; }
        if (t == 0) { b2s_ = b2[0]; bb2s_ = bb2[0]; }
    }

    // ---- parity partial sums of x[b,:] ----
    {
        float v = x[b * 512 + t] + x[b * 512 + t + 256];   // t, t+256 share parity
        #pragma unroll
        for (int msk = 2; msk <= 32; msk <<= 1) v += __shfl_xor(v, msk, 64);
        if (l < 2) pp[q][l] = v;   // lane0: even sum, lane1: odd sum (this wave's span)
    }

    const int oi = l & 31;
    const int hi = l >> 5;
    const int o  = og * 32 + oi;
    const int m  = o + 256 * hi;
    const float xv = x[b * 512 + m];
    const int hb = q * 16;

    // ---- trig: pe(m) and pe(o) ----
    float s1v[8], c1v[8], s2v[8], c2v[8];
    #pragma unroll
    for (int j = 0; j < 8; ++j) {
        float r1 = (float)m * c_rcs[j]; r1 -= floorf(r1);
        float r2 = (float)o * c_rcs[j]; r2 -= floorf(r2);
        s1v[j] = __builtin_amdgcn_sinf(r1); c1v[j] = __builtin_amdgcn_cosf(r1);
        s2v[j] = __builtin_amdgcn_sinf(r2); c2v[j] = __builtin_amdgcn_cosf(r2);
    }

    __syncthreads();

    // ---- weight MLP, this thread's 16-h slice of hidden for index m ----
    float4 hv[4];
    #pragma unroll
    for (int k = 0; k < 4; ++k) {
        const float4 bb = *(const float4*)&b1s[hb + 4 * k];
        const float4 wc = *(const float4*)&w1s[32 * 64 + hb + 4 * k];
        hv[k].x = fmaf(xv, wc.x, bb.x); hv[k].y = fmaf(xv, wc.y, bb.y);
        hv[k].z = fmaf(xv, wc.z, bb.z); hv[k].w = fmaf(xv, wc.w, bb.w);
    }
    #pragma unroll
    for (int r = 0; r < 32; ++r) {
        const float cf = (r < 16) ? ((r & 1) ? c1v[r >> 1] : s1v[r >> 1])
                                  : ((r & 1) ? c2v[(r - 16) >> 1] : s2v[(r - 16) >> 1]);
        #pragma unroll
        for (int k = 0; k < 4; ++k) {
            const float4 w = *(const float4*)&w1s[r * 64 + hb + 4 * k];  // broadcast
            hv[k].x = fmaf(cf, w.x, hv[k].x); hv[k].y = fmaf(cf, w.y, hv[k].y);
            hv[k].z = fmaf(cf, w.z, hv[k].z); hv[k].w = fmaf(cf, w.w, hv[k].w);
        }
    }
    float partial = 0.f;
    #pragma unroll
    for (int k = 0; k < 4; ++k) {
        const float4 w = *(const float4*)&w2s[hb + 4 * k];
        partial += fmaxf(hv[k].x, 0.f) * w.x + fmaxf(hv[k].y, 0.f) * w.y
                 + fmaxf(hv[k].z, 0.f) * w.z + fmaxf(hv[k].w, 0.f) * w.w;
    }
    part[q][l] = partial;
    __syncthreads();

    // ---- combine: W(b,o), W(b,o+256) from partials; out value ----
    float s0 = b2s_, s1 = b2s_;
    #pragma unroll
    for (int j = 0; j < 4; ++j) { s0 += part[j][oi]; s1 += part[j][32 + oi]; }
    const float se = pp[0][0] + pp[1][0] + pp[2][0] + pp[3][0];
    const float so = pp[0][1] + pp[1][1] + pp[2][1] + pp[3][1];
    const float outv = s0 * se + s1 * so;

    // ---- bias MLP, this thread's 16-h slice (redundant across hi halves) ----
    float4 bh[4];
    #pragma unroll
    for (int k = 0; k < 4; ++k) {
        const float4 bb = *(const float4*)&bb1s[hb + 4 * k];
        const float4 wc = *(const float4*)&bw1s[16 * 64 + hb + 4 * k];
        bh[k].x = fmaf(outv, wc.x, bb.x); bh[k].y = fmaf(outv, wc.y, bb.y);
        bh[k].z = fmaf(outv, wc.z, bb.z); bh[k].w = fmaf(outv, wc.w, bb.w);
    }
    #pragma unroll
    for (int r = 0; r < 16; ++r) {
        const float cf = (r & 1) ? c2v[r >> 1] : s2v[r >> 1];   // pe(o)
        #pragma unroll
        for (int k = 0; k < 4; ++k) {
            const float4 w = *(const float4*)&bw1s[r * 64 + hb + 4 * k];  // broadcast
            bh[k].x = fmaf(cf, w.x, bh[k].x); bh[k].y = fmaf(cf, w.y, bh[k].y);
            bh[k].z = fmaf(cf, w.z, bh[k].z); bh[k].w = fmaf(cf, w.w, bh[k].w);
        }
    }
    float partial2 = 0.f;
    #pragma unroll
    for (int k = 0; k < 4; ++k) {
        const float4 w = *(const float4*)&bw2s[hb + 4 * k];
        partial2 += fmaxf(bh[k].x, 0.f) * w.x + fmaxf(bh[k].y, 0.f) * w.y
                  + fmaxf(bh[k].z, 0.f) * w.z + fmaxf(bh[k].w, 0.f) * w.w;
    }
    if (hi == 0) part2[q][oi] = partial2;
    __syncthreads();

    if (q == 0 && hi == 0) {
        const float bias = bb2s_ + part2[0][oi] + part2[1][oi] + part2[2][oi] + part2[3][oi];
        out[b * 256 + o] = outv + bias;
    }
}

extern "C" void kernel_launch(void* const* d_in, const int* in_sizes, int n_in,
                              void* d_out, int out_size, void* d_ws, size_t ws_size,
                              hipStream_t stream) {
    const float* x   = (const float*)d_in[0];
    const float* w1  = (const float*)d_in[1];
    const float* b1  = (const float*)d_in[2];
    const float* w2  = (const float*)d_in[3];
    const float* b2  = (const float*)d_in[4];
    const float* bw1 = (const float*)d_in[5];
    const float* bb1 = (const float*)d_in[6];
    const float* bw2 = (const float*)d_in[7];
    const float* bb2 = (const float*)d_in[8];
    float* out = (float*)d_out;

    vnn_fused<<<256, 256, 0, stream>>>(x, w1, b1, w2, b2, bw1, bb1, bw2, bb2, out);
}

// Round 5
// 9.715 us; speedup vs baseline: 2.8968x; 1.1648x over previous
//
#include <hip/hip_runtime.h>
#include <math.h>

// One block per output column o = blockIdx.x (256 blocks = 1/CU).
// out[b,o] = W(b,o)*se_b + W(b,o+256)*so_b + bias(b,o), where
//   W(b,m)  = relu(PE1[m] + x[b,m]*w1[32]) @ w2 + b2
//   PE1[m]  = pe(m)@w1[0:16] + pe(o)@w1[16:32] + b1        (batch-independent)
//   bias    = relu(PEO[o] + out*bw1[16] + ... ) @ bw2 + bb2, PEO[o] = pe(o)@bw1[0:16] + bb1
//   se/so   = sums of even/odd-indexed x[b,:]
// Block builds only the 3 PE rows it needs (waves 0-2, coalesced global reads),
// then thread t=(batch bt=t>>3, h-slice s8=t&7) does the per-batch work with
// butterfly shuffles; a single __syncthreads in the whole kernel.

// c_rcs[q] = 10000^(-q/8) / (2*pi)   (v_sin/v_cos take revolutions)
__device__ __constant__ float c_rcs[8] = {
    0.15915494309189535f,   0.05032921210448703f,
    0.015915494309189535f,  0.005032921210448703f,
    0.0015915494309189535f, 0.0005032921210448703f,
    0.00015915494309189535f, 5.0329212104487035e-05f };

__device__ inline void pe_trig(int idx, float* s, float* c) {
    #pragma unroll
    for (int q = 0; q < 8; ++q) {
        float r = (float)idx * c_rcs[q];
        r -= floorf(r);
        s[q] = __builtin_amdgcn_sinf(r);
        c[q] = __builtin_amdgcn_cosf(r);
    }
}

__global__ __launch_bounds__(256) void vnn_fused(
    const float* __restrict__ x,
    const float* __restrict__ w1,  const float* __restrict__ b1,
    const float* __restrict__ w2,  const float* __restrict__ b2,
    const float* __restrict__ bw1, const float* __restrict__ bb1,
    const float* __restrict__ bw2, const float* __restrict__ bb2,
    float* __restrict__ out)
{
    __shared__ __attribute__((aligned(16))) float PE1s[2][64];
    __shared__ __attribute__((aligned(16))) float PEOs[64];
    __shared__ __attribute__((aligned(16))) float w1cS[64], w2S[64], bwcS[64], bw2S[64];
    __shared__ float ses[32], sos[32];
    __shared__ float b2s_, bb2s_;

    const int t  = threadIdx.x;
    const int j  = blockIdx.x;      // output column o = j
    const int l  = t & 63;
    const int w  = t >> 6;          // wave id
    const int bt = t >> 3;          // batch
    const int s8 = t & 7;           // h-slice id (8 hidden units each)

    // ---- parity sums of x[bt,:] (8 lanes per batch, 64 floats each) ----
    {
        float pesum = 0.f, posum = 0.f;
        const float4* xp = (const float4*)(x + bt * 512 + s8 * 64);
        #pragma unroll
        for (int q = 0; q < 16; ++q) {
            const float4 v = xp[q];
            pesum += v.x + v.z;
            posum += v.y + v.w;
        }
        #pragma unroll
        for (int mask = 1; mask <= 4; mask <<= 1) {
            pesum += __shfl_xor(pesum, mask);
            posum += __shfl_xor(posum, mask);
        }
        if (s8 == 0) { ses[bt] = pesum; sos[bt] = posum; }
    }

    // per-batch x entries used by the weight MLP (uniform across the 8 lanes)
    const float xv0 = x[bt * 512 + j];
    const float xv1 = x[bt * 512 + j + 256];

    // ---- build the 3 PE rows + stage small vectors (one wave each) ----
    if (w == 0) {
        // PE1 row for m = j: pe1(m)=pe(j), pe2(o)=pe(j)
        float s[8], c[8];
        pe_trig(j, s, c);
        float a = b1[l];
        #pragma unroll
        for (int q = 0; q < 8; ++q) {
            a = fmaf(s[q], w1[(2 * q)      * 64 + l], a);
            a = fmaf(c[q], w1[(2 * q + 1)  * 64 + l], a);
            a = fmaf(s[q], w1[(16 + 2 * q) * 64 + l], a);
            a = fmaf(c[q], w1[(17 + 2 * q) * 64 + l], a);
        }
        PE1s[0][l] = a;
    } else if (w == 1) {
        // PE1 row for m = j + 256: pe1 = pe(j+256), pe2 = pe(j)
        float s1v[8], c1v[8], s2v[8], c2v[8];
        pe_trig(j + 256, s1v, c1v);
        pe_trig(j,       s2v, c2v);
        float a = b1[l];
        #pragma unroll
        for (int q = 0; q < 8; ++q) {
            a = fmaf(s1v[q], w1[(2 * q)      * 64 + l], a);
            a = fmaf(c1v[q], w1[(2 * q + 1)  * 64 + l], a);
            a = fmaf(s2v[q], w1[(16 + 2 * q) * 64 + l], a);
            a = fmaf(c2v[q], w1[(17 + 2 * q) * 64 + l], a);
        }
        PE1s[1][l] = a;
    } else if (w == 2) {
        // PEO row for o = j
        float s[8], c[8];
        pe_trig(j, s, c);
        float a = bb1[l];
        #pragma unroll
        for (int q = 0; q < 8; ++q) {
            a = fmaf(s[q], bw1[(2 * q)     * 64 + l], a);
            a = fmaf(c[q], bw1[(2 * q + 1) * 64 + l], a);
        }
        PEOs[l] = a;
    } else {
        w1cS[l] = w1[32 * 64 + l];
        w2S[l]  = w2[l];
        bwcS[l] = bw1[16 * 64 + l];
        bw2S[l] = bw2[l];
        if (l == 0) { b2s_ = b2[0]; bb2s_ = bb2[0]; }
    }

    __syncthreads();

    // ---- weight MLP: W(bt, j) and W(bt, j+256), 8 hidden units per lane ----
    float a0 = 0.f, a1 = 0.f;
    #pragma unroll
    for (int kk = 0; kk < 2; ++kk) {
        const int base = s8 * 8 + kk * 4;
        const float4 p0 = *(const float4*)&PE1s[0][base];
        const float4 p1 = *(const float4*)&PE1s[1][base];
        const float4 wc = *(const float4*)&w1cS[base];
        const float4 wv = *(const float4*)&w2S[base];
        a0 += fmaxf(fmaf(xv0, wc.x, p0.x), 0.f) * wv.x;
        a0 += fmaxf(fmaf(xv0, wc.y, p0.y), 0.f) * wv.y;
        a0 += fmaxf(fmaf(xv0, wc.z, p0.z), 0.f) * wv.z;
        a0 += fmaxf(fmaf(xv0, wc.w, p0.w), 0.f) * wv.w;
        a1 += fmaxf(fmaf(xv1, wc.x, p1.x), 0.f) * wv.x;
        a1 += fmaxf(fmaf(xv1, wc.y, p1.y), 0.f) * wv.y;
        a1 += fmaxf(fmaf(xv1, wc.z, p1.z), 0.f) * wv.z;
        a1 += fmaxf(fmaf(xv1, wc.w, p1.w), 0.f) * wv.w;
    }
    #pragma unroll
    for (int mask = 1; mask <= 4; mask <<= 1) {
        a0 += __shfl_xor(a0, mask);
        a1 += __shfl_xor(a1, mask);
    }
    const float outv = (a0 + b2s_) * ses[bt] + (a1 + b2s_) * sos[bt];

    // ---- bias MLP for (bt, o=j) ----
    float bacc = 0.f;
    #pragma unroll
    for (int kk = 0; kk < 2; ++kk) {
        const int base = s8 * 8 + kk * 4;
        const float4 p  = *(const float4*)&PEOs[base];
        const float4 wc = *(const float4*)&bwcS[base];
        const float4 wv = *(const float4*)&bw2S[base];
        bacc += fmaxf(fmaf(outv, wc.x, p.x), 0.f) * wv.x;
        bacc += fmaxf(fmaf(outv, wc.y, p.y), 0.f) * wv.y;
        bacc += fmaxf(fmaf(outv, wc.z, p.z), 0.f) * wv.z;
        bacc += fmaxf(fmaf(outv, wc.w, p.w), 0.f) * wv.w;
    }
    #pragma unroll
    for (int mask = 1; mask <= 4; mask <<= 1) bacc += __shfl_xor(bacc, mask);

    if (s8 == 0) out[bt * 256 + j] = outv + bacc + bb2s_;
}

extern "C" void kernel_launch(void* const* d_in, const int* in_sizes, int n_in,
                              void* d_out, int out_size, void* d_ws, size_t ws_size,
                              hipStream_t stream) {
    const float* x   = (const float*)d_in[0];
    const float* w1  = (const float*)d_in[1];
    const float* b1  = (const float*)d_in[2];
    const float* w2  = (const float*)d_in[3];
    const float* b2  = (const float*)d_in[4];
    const float* bw1 = (const float*)d_in[5];
    const float* bb1 = (const float*)d_in[6];
    const float* bw2 = (const float*)d_in[7];
    const float* bb2 = (const float*)d_in[8];
    float* out = (float*)d_out;

    vnn_fused<<<256, 256, 0, stream>>>(x, w1, b1, w2, b2, bw1, bb1, bw2, bb2, out);
}